// Round 12
// baseline (187.267 us; speedup 1.0000x reference)
//
#include <hip/hip_runtime.h>

#define OUT 7
#define NCH 256
#define NROI 512
#define NS 14            // bilinear samples per axis (7 bins x 2)
#define NT 28            // tap slots per axis (lo/hi per sample)
#define CCH 8            // channels per block
#define W5 5             // LDS words per row-slot within a col-slot: 4 cp + 1 pad
#define WPC5 141         // LDS words per col-slot: 28*5 + 1 (odd -> conflict-free)
#define TPR (NCH * OUT * OUT)
#define TBL 128          // per-RoI table words: rows[28] cols[28] ly[14] vy[14] lx[14] vx[14] level

__device__ __forceinline__ unsigned int cvt_pk_bf16(float lo, float hi) {
    unsigned int r;
    asm("v_cvt_pk_bf16_f32 %0, %1, %2" : "=v"(r) : "v"(lo), "v"(hi));
    return r;
}

// One 1-D bilinear tap: sample sidx of 14 — VERBATIM the main-kernel math of
// R9/R11 (bit-identical values -> bit-identical output).
__device__ __forceinline__ void tap1d(float start, float bin, int sidx, int H,
                                      int& lo, int& hi, float& fr, float& vv) {
    int p = sidx >> 1, half = sidx & 1;
    float c = start + ((float)p + (half ? 0.75f : 0.25f)) * bin;
    vv = (c >= -1.0f && c <= (float)H) ? 0.5f : 0.0f;   // vy*vx = 0.25
    c = fmaxf(c, 0.0f);
    int l = (int)c;
    if (l >= H - 1) { lo = H - 1; hi = H - 1; fr = 0.0f; }
    else            { lo = l;     hi = l + 1; fr = c - (float)l; }
}

// ---------------------------------------------------------------------------
// Pre-pass (1 block, 512 threads): (a) sort RoIs by (image, level, y, x) —
// proven FETCH 187->34 MB with the channel-sliced mapping; (b) per-RoI tap
// TABLE (rows/cols/weights/level) so the 16384 main blocks stop recomputing
// identical box meta + tap math 32x per RoI (R11: VALU-instruction-bound,
// VALUBusy 63%). Table indexed by TRUE RoI id.
// ---------------------------------------------------------------------------
__global__ __launch_bounds__(NROI) void roi_prep_kernel(
        const float* __restrict__ boxes, int* __restrict__ ws) {
    __shared__ unsigned int keys[NROI];
    int i = (int)threadIdx.x;

    float bx1 = boxes[i * 4 + 0], by1 = boxes[i * 4 + 1];
    float bx2 = boxes[i * 4 + 2], by2 = boxes[i * 4 + 3];
    float area = (bx2 - bx1) * (by2 - by1);
    float s    = sqrtf(area);
    float lvl  = floorf(4.0f + log2f(s * (1.0f / 224.0f) + 1e-6f));
    lvl        = fminf(fmaxf(lvl, 2.0f), 5.0f);
    int level  = (int)lvl - 2;

    float scale, Hf; int H;
    switch (level) {
        case 0:  H = 200; scale = 0.25f;    break;
        case 1:  H = 100; scale = 0.125f;   break;
        case 2:  H = 50;  scale = 0.0625f;  break;
        default: H = 25;  scale = 0.03125f; break;
    }
    Hf = (float)H;

    float x1 = bx1 * scale, y1 = by1 * scale;
    float roi_w = fmaxf(bx2 * scale - x1, 1.0f);
    float roi_h = fmaxf(by2 * scale - y1, 1.0f);
    float bin_w = roi_w * (1.0f / OUT);
    float bin_h = roi_h * (1.0f / OUT);

    // ---- locality sort key ----
    float xn = 0.5f * (bx1 + bx2) * scale / Hf;   // normalized center
    float yn = 0.5f * (by1 + by2) * scale / Hf;
    int kx = (int)(xn * 8.0f); kx = kx < 0 ? 0 : (kx > 7 ? 7 : kx);
    int ky = (int)(yn * 8.0f); ky = ky < 0 ? 0 : (ky > 7 ? 7 : ky);
    int img = i >> 8;
    keys[i] = ((unsigned)img << 17) | ((unsigned)level << 15) |
              ((unsigned)ky << 12)  | ((unsigned)kx << 9) | (unsigned)i;

    for (unsigned k = 2; k <= NROI; k <<= 1) {
        for (unsigned j = k >> 1; j > 0; j >>= 1) {
            __syncthreads();
            unsigned ixj = (unsigned)i ^ j;
            if (ixj > (unsigned)i) {
                unsigned a = keys[i], b = keys[ixj];
                bool up = ((i & k) == 0);
                if ((a > b) == up) { keys[i] = b; keys[ixj] = a; }
            }
        }
    }
    __syncthreads();
    ws[i] = (int)(keys[i] & 511u);

    // ---- per-RoI tap table (thread i -> RoI i) ----
    int* t = ws + NROI + i * TBL;
    for (int sy = 0; sy < NS; ++sy) {
        int lo, hi; float fr, vv;
        tap1d(y1, bin_h, sy, H, lo, hi, fr, vv);
        t[2 * sy]     = lo;
        t[2 * sy + 1] = hi;
        t[56 + sy] = __float_as_int(fr);
        t[70 + sy] = __float_as_int(vv);
    }
    for (int sx = 0; sx < NS; ++sx) {
        int lo, hi; float fr, vv;
        tap1d(x1, bin_w, sx, H, lo, hi, fr, vv);
        t[28 + 2 * sx]     = lo;
        t[28 + 2 * sx + 1] = hi;
        t[84 + sx] = __float_as_int(fr);
        t[98 + sx] = __float_as_int(vv);
    }
    t[112] = level;
}

// Block = (sorted RoI, 8-channel chunk), channel-sliced across XCDs
// (xcd=g&7, sidx=g>>5, q=((g>>3)&3)*8+xcd): per-XCD L2 working set 8x
// smaller, perfect balance, consecutive blocks share footprints (R11:
// FETCH 34 MB, 60 us). NEW: all per-RoI math comes from the precomputed
// table (one coalesced 128-word read into LDS) — no boxes load, no meta,
// no tap math in the hot kernel. Gather + staging + pooling unchanged.
// LDS word index: colslot*141 + rowslot*5 + cp  (cp = channel pair 0..3).
__global__ __launch_bounds__(256, 8) void roi_align_tap8_kernel(
        const float* __restrict__ f0, const float* __restrict__ f1,
        const float* __restrict__ f2, const float* __restrict__ f3,
        const int* __restrict__ ws, float* __restrict__ out) {
    __shared__ __align__(16) unsigned int sm32[NT * WPC5];   // 15,792 B
    __shared__ int tS[TBL];

    int g    = blockIdx.x;
    int xcd  = g & 7;
    int sidx = g >> 5;                  // sorted slot 0..511
    int sub  = (g >> 3) & 3;
    int q    = sub * 8 + xcd;           // chunk: XCD x owns {x,8+x,16+x,24+x}
    int r    = __builtin_amdgcn_readfirstlane(ws[sidx]);   // true RoI id
    int tid  = (int)threadIdx.x;

    // ---------------- load per-RoI table (one coalesced read) --------------
    if (tid < TBL) tS[tid] = ws[NROI + r * TBL + tid];
    __syncthreads();

    int level = __builtin_amdgcn_readfirstlane(tS[112]);
    const float* f; int H;
    switch (level) {
        case 0:  f = f0; H = 200; break;
        case 1:  f = f1; H = 100; break;
        case 2:  f = f2; H = 50;  break;
        default: f = f3; H = 25;  break;
    }

    // ---------------- phase 2a: per-lane tap addresses + ISSUE all loads ----
    int bidx = r >> 8;   // 256 RoIs per batch image
    size_t HH = (size_t)(H * H);
    const float* plane = f + (size_t)(bidx * NCH + q * CCH) * HH;

    int lane = tid & 63;
    int wave = tid >> 6;
    // lanes 0..27: colslot j, cg=0 (ch 0..3); lanes 28..55: colslot j, cg=1
    int  j   = (lane < 28) ? lane : ((lane < 56) ? lane - 28 : lane - 56);
    int  cg  = (lane >= 28 && lane < 56) ? 1 : 0;
    bool act = (lane < 56);

    int col = tS[28 + j];

    int roff[7];
#pragma unroll
    for (int t = 0; t < 7; ++t)
        roff[t] = tS[wave * 7 + t] * H + col;

    const float* base = plane + (size_t)(cg * 4) * HH;   // ch 4cg..4cg+3

    // issue all 28 tap loads (7 rows x 4 channels) before the convert region
    float v[7][4];
#pragma unroll
    for (int t = 0; t < 7; ++t)
#pragma unroll
        for (int cc = 0; cc < 4; ++cc)
            v[t][cc] = base[(size_t)cc * HH + (size_t)roff[t]];
    asm volatile("" ::: "memory");
    __builtin_amdgcn_sched_barrier(0);

    // ---------------- phase 2b: convert + stage into LDS ----------------
#pragma unroll
    for (int t = 0; t < 7; ++t) {
        int rs = wave * 7 + t;                     // row slot 0..27
        unsigned int w01 = cvt_pk_bf16(v[t][0], v[t][1]);
        unsigned int w23 = cvt_pk_bf16(v[t][2], v[t][3]);
        if (act) {
            unsigned int* d0 = sm32 + j * WPC5 + rs * W5 + 2 * cg;
            d0[0] = w01;   // cp 2cg   (ch 4cg, 4cg+1)
            d0[1] = w23;   // cp 2cg+1 (ch 4cg+2, 4cg+3)
        }
    }
    __syncthreads();

    // ---------------- phase 3: pool 49 px x 4 channel-pairs ----------------
    float accx = 0.0f, accy = 0.0f;
    int o = tid;
    if (o < 196) {
        int cp = o & 3, px = o >> 2;
        int ph = px / 7, pw2 = px - ph * 7;
        float ax = 0.0f, ay = 0.0f;
#pragma unroll
        for (int iy = 0; iy < 2; ++iy) {
            int sy = ph * 2 + iy;
            float ly = __int_as_float(tS[56 + sy]), hy = 1.0f - ly;
            float vy = __int_as_float(tS[70 + sy]);
            int r0 = (2 * sy) * W5 + cp;
            int r1 = r0 + W5;
#pragma unroll
            for (int ix = 0; ix < 2; ++ix) {
                int sx = pw2 * 2 + ix;
                float lx = __int_as_float(tS[84 + sx]), hx = 1.0f - lx;
                float m  = vy * __int_as_float(tS[98 + sx]);  // 0.25 if valid
                int c0i = (2 * sx) * WPC5;
                int c1i = c0i + WPC5;
                unsigned int u00 = sm32[c0i + r0];
                unsigned int u01 = sm32[c1i + r0];
                unsigned int u10 = sm32[c0i + r1];
                unsigned int u11 = sm32[c1i + r1];
                float w00 = hy * hx * m, w01 = hy * lx * m;
                float w10 = ly * hx * m, w11 = ly * lx * m;
                ax = fmaf(w00, __uint_as_float(u00 << 16), ax);
                ay = fmaf(w00, __uint_as_float(u00 & 0xFFFF0000u), ay);
                ax = fmaf(w01, __uint_as_float(u01 << 16), ax);
                ay = fmaf(w01, __uint_as_float(u01 & 0xFFFF0000u), ay);
                ax = fmaf(w10, __uint_as_float(u10 << 16), ax);
                ay = fmaf(w10, __uint_as_float(u10 & 0xFFFF0000u), ay);
                ax = fmaf(w11, __uint_as_float(u11 << 16), ax);
                ay = fmaf(w11, __uint_as_float(u11 & 0xFFFF0000u), ay);
            }
        }
        accx = ax; accy = ay;
    }
    __syncthreads();   // LDS reads done; reuse sm32 for output repack

    // ---------------- phase 4: repack via LDS, contiguous float4 store -----
    float* smf = (float*)sm32;
    if (o < 196) {
        int cp = o & 3, px = o >> 2;
        smf[(cp * 2 + 0) * 49 + px] = accx;  // even channel (low ushort)
        smf[(cp * 2 + 1) * 49 + px] = accy;  // odd channel (high ushort)
    }
    __syncthreads();

    float* dst = out + (size_t)r * TPR + (size_t)q * (CCH * 49);
    if (tid < 98)
        ((float4*)dst)[tid] = ((const float4*)smf)[tid];
}

extern "C" void kernel_launch(void* const* d_in, const int* in_sizes, int n_in,
                              void* d_out, int out_size, void* d_ws, size_t ws_size,
                              hipStream_t stream) {
    const float* f0    = (const float*)d_in[0];
    const float* f1    = (const float*)d_in[1];
    const float* f2    = (const float*)d_in[2];
    const float* f3    = (const float*)d_in[3];
    const float* boxes = (const float*)d_in[4];
    float* out         = (float*)d_out;
    int*   ws          = (int*)d_ws;    // [0..511] perm, then 512 x 128 table

    roi_prep_kernel<<<1, NROI, 0, stream>>>(boxes, ws);
    roi_align_tap8_kernel<<<NROI * 32, 256, 0, stream>>>(f0, f1, f2, f3, ws, out);
}